// Round 1
// 342.400 us; speedup vs baseline: 1.0961x; 1.0961x over previous
//
#include <hip/hip_runtime.h>
#include <hip/hip_bf16.h>

using bf16 = __hip_bfloat16;
typedef __attribute__((ext_vector_type(8))) short bf16x8;   // 8 bf16 = 4 VGPRs (MFMA A/B frag)
typedef __attribute__((ext_vector_type(4))) float f32x4;    // MFMA C/D frag

// async global->LDS, 16B per lane; LDS dest = wave-uniform base + lane*16 (m97/m104)
#define GLL(gp, lp) __builtin_amdgcn_global_load_lds( \
    (const __attribute__((address_space(1))) void*)(gp), \
    (__attribute__((address_space(3))) void*)(lp), 16, 0, 0)

#define BAR()    asm volatile("s_barrier" ::: "memory")
#define WAITV4() asm volatile("s_waitcnt vmcnt(4)" ::: "memory")
#define WAITV0() asm volatile("s_waitcnt vmcnt(0)" ::: "memory")
#define WAITL0() do { asm volatile("s_waitcnt lgkmcnt(0)" ::: "memory"); \
                      __builtin_amdgcn_sched_barrier(0); } while (0)

__device__ inline short bfbits(float f) {
  union { bf16 h; short s; } u;
  u.h = __float2bfloat16(f);
  return u.s;
}

// Load 8 contiguous fp32 at fully-formed pointer, return bf16x8.
__device__ inline bf16x8 ldcvt(const float* __restrict__ g) {
  const float4 f0 = *(const float4*)(g);
  const float4 f1 = *(const float4*)(g + 4);
  union { short s[8]; bf16x8 v; } u;
  u.s[0] = bfbits(f0.x); u.s[1] = bfbits(f0.y); u.s[2] = bfbits(f0.z); u.s[3] = bfbits(f0.w);
  u.s[4] = bfbits(f1.x); u.s[5] = bfbits(f1.y); u.s[6] = bfbits(f1.z); u.s[7] = bfbits(f1.w);
  return u.v;
}

__device__ inline void store_c(float* C, size_t idx, float v) { C[idx] = v; }
__device__ inline void store_c(bf16*  C, size_t idx, float v) { C[idx] = __float2bfloat16(v); }

// elementwise fp32 -> bf16, 8 elems/thread
__global__ __launch_bounds__(256)
void f32_to_bf16(const float* __restrict__ src, bf16* __restrict__ dst, int n8) {
  const int i = blockIdx.x * 256 + threadIdx.x;
  if (i < n8) *(bf16x8*)(dst + (size_t)i * 8) = ldcvt(src + (size_t)i * 8);
}

// ---------------------------------------------------------------------------
// OLD 128x128 2-phase kernel — kept only as the fp32-B fallback for GEMM2
// when ws_size has no headroom for a bf16 copy of Wo.
// ---------------------------------------------------------------------------
template <typename TB, typename TC>
__global__ __launch_bounds__(256)
void gemm_nt(const bf16* __restrict__ A, const TB* __restrict__ B,
             const float* __restrict__ bias, TC* __restrict__ C,
             int K, int lda, int ldb, int ldc) {
  constexpr bool B_F32 = sizeof(TB) == 4;
  __shared__ __align__(16) bf16 As[128 * 32];
  __shared__ __align__(16) bf16 Bs[128 * 32];
  const int tid  = threadIdx.x;
  const int lane = tid & 63;
  const int wave = tid >> 6;
  const int wm = wave >> 1, wn = wave & 1;
  const int m0 = blockIdx.y * 128;
  const int n0 = blockIdx.x * 128;

  const int srow = wave * 16 + (lane >> 2);
  const int scol = (lane & 3) * 8;
  const bf16* gA0 = A + (size_t)(m0 + srow) * lda + scol;
  const bf16* gA1 = A + (size_t)(m0 + 64 + srow) * lda + scol;
  const TB*   gB0 = B + (size_t)(n0 + srow) * ldb + scol;
  const TB*   gB1 = B + (size_t)(n0 + 64 + srow) * ldb + scol;
  bf16* lA0 = &As[(wave * 16) * 32];
  bf16* lA1 = lA0 + 64 * 32;
  bf16* lB0u = &Bs[(wave * 16) * 32];
  bf16* lB1u = lB0u + 64 * 32;
  bf16* lB0p = &Bs[srow * 32 + scol];
  bf16* lB1p = lB0p + 64 * 32;

  const int fr = lane & 15;
  const int kq = (lane >> 4) * 8;
  f32x4 acc[4][4] = {};

  for (int k0 = 0; k0 < K; k0 += 32) {
    bf16x8 b0, b1;
    if constexpr (B_F32) {
      b0 = ldcvt((const float*)gB0 + k0);
      b1 = ldcvt((const float*)gB1 + k0);
    }
    __syncthreads();
    GLL(gA0 + k0, lA0);
    GLL(gA1 + k0, lA1);
    if constexpr (B_F32) {
      *(bf16x8*)lB0p = b0;
      *(bf16x8*)lB1p = b1;
    } else {
      GLL((const bf16*)gB0 + k0, lB0u);
      GLL((const bf16*)gB1 + k0, lB1u);
    }
    __syncthreads();
    bf16x8 af[4], bfv[4];
#pragma unroll
    for (int t = 0; t < 4; ++t) {
      af[t]  = *(const bf16x8*)&As[(wm * 64 + t * 16 + fr) * 32 + kq];
      bfv[t] = *(const bf16x8*)&Bs[(wn * 64 + t * 16 + fr) * 32 + kq];
    }
#pragma unroll
    for (int i = 0; i < 4; ++i)
#pragma unroll
      for (int j = 0; j < 4; ++j)
        acc[i][j] = __builtin_amdgcn_mfma_f32_16x16x32_bf16(af[i], bfv[j], acc[i][j], 0, 0, 0);
  }

  const int rq  = (lane >> 4) * 4;
  const int col = lane & 15;
#pragma unroll
  for (int j = 0; j < 4; ++j) {
    const int cn = n0 + wn * 64 + j * 16 + col;
    const float bv = bias ? bias[cn] : 0.0f;
#pragma unroll
    for (int i = 0; i < 4; ++i) {
      const int cm = m0 + wm * 64 + i * 16 + rq;
#pragma unroll
      for (int r = 0; r < 4; ++r)
        store_c(C, (size_t)(cm + r) * ldc + cn, acc[i][j][r] + bv);
    }
  }
}

// ---------------------------------------------------------------------------
// 256x256 8-phase bf16 GEMM (T1 XCD-swizzle + T2 LDS swizzle + T3/T4 counted
// vmcnt + T5 setprio).  C[m,n] = sum_k A[m*lda+k]*B[n*ldb+k] (+bias[n]).
// M,N multiples of 256; K multiple of 128.  Grid: 1-D nwg = (M/256)*(N/256),
// block 512 (8 waves = 2M x 4N, each owns a 128x64 output tile).
//
// LDS: As/Bs[2][256][64] bf16 = 128 KiB total (2 K-tile double buffer).
// Staging: half-tile = 128 rows x 64 cols = 2 GLL/thread; GLL dest is LINEAR
// (wave-uniform base + lane*16); the T2 swizzle is applied by permuting the
// GLOBAL source column per lane (rule 21) and un-permuting on ds_read:
//   LDS[row, chunk] = G[row, chunk ^ (row&7)]   (chunk = 16B unit of the row)
// Read of logical chunk c at row r  ->  LDS[row, c ^ (r&7)]  => 2-way max.
//
// Phase schedule per iteration (2 K-tiles: kt0=2i in buf0, kt1=2i+1 in buf1);
// quadrants q0..q3 = (mh,nh) = (0,0),(0,1),(1,1),(1,0); per-phase stages:
//   p0: A-lo(buf1,kt1)  p1: A-hi(buf1,kt1)  p2: B-lo(buf0,kt0+2)
//   p3: B-hi(buf0,kt0+2)+vmcnt(4)           p4: A-lo(buf0,kt0+2)
//   p5: A-hi(buf0,kt0+2)                    p6: B-lo(buf1,kt1+2)
//   p7: B-hi(buf1,kt1+2)+vmcnt(4)
// Every region is restaged >=1 barrier after its last ds_read; each vmcnt(4)
// leaves exactly the 2 not-yet-needed half-tiles in flight.  Tail iterations
// clamp the prefetch kt to 0 (must keep 2 loads/phase for the vmcnt count).
// ---------------------------------------------------------------------------
template <typename TC>
__global__ __launch_bounds__(512)
void gemm256(const bf16* __restrict__ A, const bf16* __restrict__ B,
             const float* __restrict__ bias, TC* __restrict__ C,
             int K, int lda, int ldb, int ldc, int nbx) {
  __shared__ __align__(16) bf16 As[2][256][64];
  __shared__ __align__(16) bf16 Bs[2][256][64];
  const int tid  = threadIdx.x;
  const int lane = tid & 63;
  const int wave = tid >> 6;          // 0..7
  const int wm = wave >> 2;           // 0..1 : rows [wm*128, +128)
  const int wn = wave & 3;            // 0..3 : cols [wn*64, +64)

  // T1: bijective XCD swizzle (nwg % 8 == 0 in all our launches)
  int wg = blockIdx.x;
  const int nwg = gridDim.x;
  if ((nwg & 7) == 0) wg = (wg & 7) * (nwg >> 3) + (wg >> 3);
  const int m0 = (wg / nbx) * 256;
  const int n0 = (wg % nbx) * 256;

  // staging map: lane l of wave w, round r covers LDS row r*64 + w*8 + (l>>3),
  // 16B chunk (l&7); global source column pre-swizzled by chunk ^ (row&7).
  const int srow = wave * 8 + (lane >> 3);
  const int scol = ((lane & 7) ^ (lane >> 3)) * 8;   // pre-swizzled (elems)
  const bf16* gA = A + (size_t)(m0 + srow) * lda + scol;
  const bf16* gB = B + (size_t)(n0 + srow) * ldb + scol;

  const int fr = lane & 15, quad = lane >> 4, swz = fr & 7;

#define STAGE_A(buf, h, kt) do { \
    GLL(gA + (size_t)((h) * 128     ) * lda + (kt) * 64, &As[buf][(h) * 128      + wave * 8][0]); \
    GLL(gA + (size_t)((h) * 128 + 64) * lda + (kt) * 64, &As[buf][(h) * 128 + 64 + wave * 8][0]); \
  } while (0)
#define STAGE_B(buf, h, kt) do { \
    GLL(gB + (size_t)((h) * 128     ) * ldb + (kt) * 64, &Bs[buf][(h) * 128      + wave * 8][0]); \
    GLL(gB + (size_t)((h) * 128 + 64) * ldb + (kt) * 64, &Bs[buf][(h) * 128 + 64 + wave * 8][0]); \
  } while (0)
// A frag group mh (4 m-tiles x 2 ksteps = 8 x ds_read_b128, swizzled chunk)
#define LDA_G(buf, mh) do { _Pragma("unroll") \
    for (int t = 0; t < 4; ++t) { _Pragma("unroll") \
      for (int ks = 0; ks < 2; ++ks) \
        av[t * 2 + ks] = *(const bf16x8*)&As[buf][wm * 128 + (mh) * 64 + t * 16 + fr] \
                                            [(((ks << 2) | quad) ^ swz) << 3]; } } while (0)
// B frag group nh (2 n-tiles x 2 ksteps = 4 x ds_read_b128)
#define LDB_G(buf, nh, dst) do { _Pragma("unroll") \
    for (int t = 0; t < 2; ++t) { _Pragma("unroll") \
      for (int ks = 0; ks < 2; ++ks) \
        dst[t * 2 + ks] = *(const bf16x8*)&Bs[buf][wn * 64 + (nh) * 32 + t * 16 + fr] \
                                             [(((ks << 2) | quad) ^ swz) << 3]; } } while (0)
// one C-quadrant x K=64: 16 MFMAs wrapped in setprio (T5)
#define MFMA_Q(mh, nh, bb) do { \
    __builtin_amdgcn_s_setprio(1); \
    _Pragma("unroll") \
    for (int t = 0; t < 4; ++t) { _Pragma("unroll") \
      for (int u = 0; u < 2; ++u) { _Pragma("unroll") \
        for (int ks = 0; ks < 2; ++ks) \
          acc[(mh) * 4 + t][(nh) * 2 + u] = __builtin_amdgcn_mfma_f32_16x16x32_bf16( \
              av[t * 2 + ks], bb[u * 2 + ks], acc[(mh) * 4 + t][(nh) * 2 + u], 0, 0, 0); } } \
    __builtin_amdgcn_s_setprio(0); } while (0)

  bf16x8 av[8], b0[4], b1[4];
  f32x4 acc[8][4] = {};

  // prologue: buf0 <- kt0, plus B(buf1) <- kt1 (A(buf1) comes at p0/p1)
  STAGE_A(0, 0, 0); STAGE_A(0, 1, 0);
  STAGE_B(0, 0, 0); STAGE_B(0, 1, 0);
  STAGE_B(1, 0, 1); STAGE_B(1, 1, 1);
  WAITV4(); BAR();

  const int KT = K >> 6;        // K-tiles
  const int NI = KT >> 1;       // iterations (2 K-tiles each)
  for (int i = 0; i < NI; ++i) {
    const int kt1 = 2 * i + 1;
    const int ka  = (2 * i + 2 < KT) ? 2 * i + 2 : 0;   // clamped prefetch
    const int kb  = (2 * i + 3 < KT) ? 2 * i + 3 : 0;

    // p0: quadrant (0,0) on buf0
    LDA_G(0, 0); LDB_G(0, 0, b0); STAGE_A(1, 0, kt1);
    BAR(); WAITL0(); MFMA_Q(0, 0, b0); BAR();
    // p1: (0,1)
    LDB_G(0, 1, b1); STAGE_A(1, 1, kt1);
    BAR(); WAITL0(); MFMA_Q(0, 1, b1); BAR();
    // p2: (1,1)
    LDA_G(0, 1); STAGE_B(0, 0, ka);
    BAR(); WAITL0(); MFMA_Q(1, 1, b1); BAR();
    // p3: (1,0)  [b0 kept live from p0]
    STAGE_B(0, 1, ka); WAITV4();
    BAR(); WAITL0(); MFMA_Q(1, 0, b0); BAR();
    // p4: (0,0) on buf1
    LDA_G(1, 0); LDB_G(1, 0, b0); STAGE_A(0, 0, ka);
    BAR(); WAITL0(); MFMA_Q(0, 0, b0); BAR();
    // p5: (0,1)
    LDB_G(1, 1, b1); STAGE_A(0, 1, ka);
    BAR(); WAITL0(); MFMA_Q(0, 1, b1); BAR();
    // p6: (1,1)
    LDA_G(1, 1); STAGE_B(1, 0, kb);
    BAR(); WAITL0(); MFMA_Q(1, 1, b1); BAR();
    // p7: (1,0)
    STAGE_B(1, 1, kb); WAITV4();
    BAR(); WAITL0(); MFMA_Q(1, 0, b0); BAR();
  }
  WAITV0();   // drain tail GLLs before waves can exit (LDS dealloc safety)

  // epilogue: C/D layout col = lane&15, row = quad*4 + r (verified m89/m91)
  const int rq = quad * 4;
#pragma unroll
  for (int nj = 0; nj < 4; ++nj) {
    const int cn = n0 + wn * 64 + nj * 16 + fr;
    const float bv = bias ? bias[cn] : 0.0f;
#pragma unroll
    for (int mi = 0; mi < 8; ++mi) {
      const int cm = m0 + wm * 128 + mi * 16 + rq;
#pragma unroll
      for (int r = 0; r < 4; ++r)
        store_c(C, (size_t)(cm + r) * ldc + cn, acc[mi][nj][r] + bv);
    }
  }
#undef STAGE_A
#undef STAGE_B
#undef LDA_G
#undef LDB_G
#undef MFMA_Q
}

// Per-token head-attention on the bf16 qkv workspace.
// qkv row = [q(16x64) | k(16x64) | v(16x64)]. One wave per token. attn -> q slot.
__global__ __launch_bounds__(256)
void attn_heads(bf16* __restrict__ qkv) {
  __shared__ __align__(16) bf16  s_qkv[4][3072];
  __shared__ __align__(16) float s_w[4][256];
  const int lane = threadIdx.x & 63;
  const int wave = threadIdx.x >> 6;
  const size_t tok = (size_t)blockIdx.x * 4 + wave;
  bf16* grow = qkv + tok * 3072;

#pragma unroll
  for (int i = 0; i < 6; ++i) {
    const int off = (i * 64 + lane) * 8;
    *(uint4*)(&s_qkv[wave][off]) = *(const uint4*)(&grow[off]);
  }
  __syncthreads();

  const bf16* sq = s_qkv[wave];
  const int fr   = lane & 15;
  const int quad = lane >> 4;

  f32x4 sc = {0.f, 0.f, 0.f, 0.f};
#pragma unroll
  for (int c = 0; c < 2; ++c) {
    bf16x8 a = *(const bf16x8*)&sq[fr * 64 + c * 32 + quad * 8];
    bf16x8 b = *(const bf16x8*)&sq[1024 + fr * 64 + c * 32 + quad * 8];
    sc = __builtin_amdgcn_mfma_f32_16x16x32_bf16(a, b, sc, 0, 0, 0);
  }

#pragma unroll
  for (int r = 0; r < 4; ++r) {
    float s = sc[r] * 0.03125f;       // 1/sqrt(1024)
    float mx = s;
#pragma unroll
    for (int msk = 1; msk < 16; msk <<= 1) mx = fmaxf(mx, __shfl_xor(mx, msk, 64));
    float e = __expf(s - mx);
    float sum = e;
#pragma unroll
    for (int msk = 1; msk < 16; msk <<= 1) sum += __shfl_xor(sum, msk, 64);
    s_w[wave][(quad * 4 + r) * 16 + fr] = e / sum;
  }
  __syncthreads();

  float vv[16];
#pragma unroll
  for (int g = 0; g < 16; ++g) vv[g] = __bfloat162float(sq[2048 + g * 64 + lane]);
  const float* wrow = s_w[wave];
#pragma unroll
  for (int h = 0; h < 16; ++h) {
    float o = 0.f;
#pragma unroll
    for (int g4 = 0; g4 < 4; ++g4) {
      f32x4 w4 = *(const f32x4*)&wrow[h * 16 + g4 * 4];
      o += w4.x * vv[g4 * 4 + 0] + w4.y * vv[g4 * 4 + 1] +
           w4.z * vv[g4 * 4 + 2] + w4.w * vv[g4 * 4 + 3];
    }
    grow[h * 64 + lane] = __float2bfloat16(o);
  }
}

extern "C" void kernel_launch(void* const* d_in, const int* in_sizes, int n_in,
                              void* d_out, int out_size, void* d_ws, size_t ws_size,
                              hipStream_t stream) {
  const float* x    = (const float*)d_in[0];   // (4,4096,1024) fp32
  const float* Wqkv = (const float*)d_in[1];   // (3072,1024) fp32
  const float* Wo   = (const float*)d_in[2];   // (1024,1024) fp32
  const float* bo   = (const float*)d_in[3];   // (1024,) fp32
  float* out = (float*)d_out;                  // (4,4096,1024) fp32, 64 MiB
  bf16* qkv  = (bf16*)d_ws;                    // 16384 x 3072 bf16 = 96 MiB

  // d_out doubles as pre-GEMM2 scratch: x_bf16 (32 MiB) + Wqkv_bf16 (6 MiB);
  // both dead before GEMM2 overwrites d_out (in-stream serialization).
  bf16* xb    = (bf16*)d_out;                  // 16,777,216 elems
  bf16* wqkvb = xb + 16777216;                 //  3,145,728 elems

  // Wo_bf16 must stay live DURING GEMM2 (which writes all of d_out), so it
  // needs workspace headroom past qkv; fall back to fp32-B path if absent.
  const size_t qkv_bytes = (size_t)16384 * 3072 * 2;          // 96 MiB
  const bool have_ws = ws_size >= qkv_bytes + (size_t)2 * 1024 * 1024;
  bf16* wob = (bf16*)((char*)d_ws + qkv_bytes);

  // 0) one-time fp32 -> bf16 conversions
  f32_to_bf16<<<16777216 / 8 / 256, 256, 0, stream>>>(x, xb, 16777216 / 8);
  f32_to_bf16<<<3145728 / 8 / 256, 256, 0, stream>>>(Wqkv, wqkvb, 3145728 / 8);
  if (have_ws)
    f32_to_bf16<<<1048576 / 8 / 256, 256, 0, stream>>>(Wo, wob, 1048576 / 8);

  // 1) qkv = xb @ wqkvb^T  (M=16384, N=3072, K=1024) — 8-phase 256^2
  gemm256<bf16><<<(3072 / 256) * (16384 / 256), 512, 0, stream>>>(
      xb, wqkvb, nullptr, qkv, 1024, 1024, 1024, 3072, 3072 / 256);

  // 2) per-token head attention, attn -> q slot (stride 3072)
  attn_heads<<<dim3(16384 / 4), 256, 0, stream>>>(qkv);

  // 3) out = attn @ Wo^T + bo  (M=16384, N=1024, K=1024, lda=3072)
  if (have_ws)
    gemm256<float><<<(1024 / 256) * (16384 / 256), 512, 0, stream>>>(
        qkv, wob, bo, out, 1024, 3072, 1024, 1024, 1024 / 256);
  else
    gemm_nt<float, float><<<dim3(1024 / 128, 16384 / 128), 256, 0, stream>>>(
        qkv, Wo, bo, out, 1024, 3072, 1024, 1024);
}

// Round 2
// 288.695 us; speedup vs baseline: 1.3000x; 1.1860x over previous
//
#include <hip/hip_runtime.h>
#include <hip/hip_bf16.h>

using bf16 = __hip_bfloat16;
typedef __attribute__((ext_vector_type(8))) short bf16x8;   // 8 bf16 = 4 VGPRs (MFMA A/B frag)
typedef __attribute__((ext_vector_type(4))) float f32x4;    // MFMA C/D frag

// async global->LDS, 16B per lane; LDS dest = wave-uniform base + lane*16 (m97/m104)
#define GLL(gp, lp) __builtin_amdgcn_global_load_lds( \
    (const __attribute__((address_space(1))) void*)(gp), \
    (__attribute__((address_space(3))) void*)(lp), 16, 0, 0)

#define BAR()    asm volatile("s_barrier" ::: "memory")
#define WAITV4() asm volatile("s_waitcnt vmcnt(4)" ::: "memory")
#define WAITV6() asm volatile("s_waitcnt vmcnt(6)" ::: "memory")
#define WAITV0() asm volatile("s_waitcnt vmcnt(0)" ::: "memory")
#define WAITL0() do { asm volatile("s_waitcnt lgkmcnt(0)" ::: "memory"); \
                      __builtin_amdgcn_sched_barrier(0); } while (0)
#define LHINT8() asm volatile("s_waitcnt lgkmcnt(8)" ::: "memory")

__device__ inline short bfbits(float f) {
  union { bf16 h; short s; } u;
  u.h = __float2bfloat16(f);
  return u.s;
}

// Load 8 contiguous fp32 at fully-formed pointer, return bf16x8.
__device__ inline bf16x8 ldcvt(const float* __restrict__ g) {
  const float4 f0 = *(const float4*)(g);
  const float4 f1 = *(const float4*)(g + 4);
  union { short s[8]; bf16x8 v; } u;
  u.s[0] = bfbits(f0.x); u.s[1] = bfbits(f0.y); u.s[2] = bfbits(f0.z); u.s[3] = bfbits(f0.w);
  u.s[4] = bfbits(f1.x); u.s[5] = bfbits(f1.y); u.s[6] = bfbits(f1.z); u.s[7] = bfbits(f1.w);
  return u.v;
}

// elementwise fp32 -> bf16, 8 elems/thread
__global__ __launch_bounds__(256)
void f32_to_bf16(const float* __restrict__ src, bf16* __restrict__ dst, int n8) {
  const int i = blockIdx.x * 256 + threadIdx.x;
  if (i < n8) *(bf16x8*)(dst + (size_t)i * 8) = ldcvt(src + (size_t)i * 8);
}

// ---------------------------------------------------------------------------
// 256x256 8-phase bf16 GEMM.  C[m,n] = sum_k A[m*lda+k]*B[n*ldb+k] (+bias[n]).
// M,N multiples of 256; K multiple of 128.  Grid: 1-D nwg, block 512
// (8 waves = 2M x 4N, each owns a 128x64 output tile).
//
// SPLIT3 (GEMM1): logical C column cn is routed to plane cn>>10 at
//   C + (plane<<24) + m*1024 + (cn&1023)   (plane stride 16384*1024 = 1<<24).
//
// LDS: smem[4][256][64] bf16 = 128 KiB; A bufs = smem[0..1], B = smem[2..3].
// T2 swizzle: linear GLL dest + pre-swizzled global source column; ds_read
// un-permutes: LDS[row,chunk] = G[row, chunk ^ (row&7)] (chunk = 16B unit).
//
// Stage schedule (derived-waits; write-after-read constraints):
//   region last-read -> earliest restage:  B0:p1->p2  A0:p2->p3  B1:p5->p6
//   A1:p6->p7.   Stages: p0:A1hi(kt1)  p2:B0lo'  p3:B0hi'  p4:A0lo'
//   p5:A0hi'  p6:B1lo'  p7:B1hi'+A1lo'(next kt1).
// Waits: vmcnt(4)@p3 covers buf1 (oldest 8 = B1(4)+A1lo(2)+A1hi(2), all
//   issued >=3 phases prior); vmcnt(6)@p7 covers buf0 (B0'+A0'), leaving
//   3 half-tiles (B1'+A1lo') in flight — matches the m201 template's N=6.
// Prologue: A0,B0,B1,A1lo (14 loads) -> vmcnt(6).  Tail prefetch clamps to
//   kt=0 (dummy but keeps the vmcnt ledger exact).
// ---------------------------------------------------------------------------
template <typename TC, bool SPLIT3>
__global__ __launch_bounds__(512)
void gemm256(const bf16* __restrict__ A, const bf16* __restrict__ B,
             const float* __restrict__ bias, TC* __restrict__ C,
             int K, int lda, int ldb, int ldc, int nbx) {
  __shared__ __align__(16) bf16 smem[4][256][64];
  const int tid  = threadIdx.x;
  const int lane = tid & 63;
  const int wave = tid >> 6;          // 0..7
  const int wm = wave >> 2;           // 0..1 : rows [wm*128, +128)
  const int wn = wave & 3;            // 0..3 : cols [wn*64, +64)

  // T1: bijective XCD swizzle (nwg % 8 == 0 in all our launches)
  int wg = blockIdx.x;
  const int nwg = gridDim.x;
  if ((nwg & 7) == 0) wg = (wg & 7) * (nwg >> 3) + (wg >> 3);
  const int m0 = (wg / nbx) * 256;
  const int n0 = (wg % nbx) * 256;

  // staging map: lane l of wave w covers LDS row (h-block + w*8 + (l>>3)),
  // 16B chunk (l&7); global source column pre-swizzled by chunk ^ (row&7).
  const int srow = wave * 8 + (lane >> 3);
  const int scol = ((lane & 7) ^ (lane >> 3)) * 8;   // pre-swizzled (elems)
  const bf16* gA = A + (size_t)(m0 + srow) * lda + scol;
  const bf16* gB = B + (size_t)(n0 + srow) * ldb + scol;

  const int fr = lane & 15, quad = lane >> 4, swz = fr & 7;

#define STAGE_A(buf, h, kt) do { \
    GLL(gA + (size_t)((h) * 128     ) * lda + (kt) * 64, &smem[buf][(h) * 128      + wave * 8][0]); \
    GLL(gA + (size_t)((h) * 128 + 64) * lda + (kt) * 64, &smem[buf][(h) * 128 + 64 + wave * 8][0]); \
  } while (0)
#define STAGE_B(buf, h, kt) do { \
    GLL(gB + (size_t)((h) * 128     ) * ldb + (kt) * 64, &smem[2 + (buf)][(h) * 128      + wave * 8][0]); \
    GLL(gB + (size_t)((h) * 128 + 64) * ldb + (kt) * 64, &smem[2 + (buf)][(h) * 128 + 64 + wave * 8][0]); \
  } while (0)
// A frag group mh (4 m-tiles x 2 ksteps = 8 x ds_read_b128, swizzled chunk)
#define LDA_G(buf, mh) do { _Pragma("unroll") \
    for (int t = 0; t < 4; ++t) { _Pragma("unroll") \
      for (int ks = 0; ks < 2; ++ks) \
        av[t * 2 + ks] = *(const bf16x8*)&smem[buf][wm * 128 + (mh) * 64 + t * 16 + fr] \
                                             [(((ks << 2) | quad) ^ swz) << 3]; } } while (0)
// B frag group nh (2 n-tiles x 2 ksteps = 4 x ds_read_b128)
#define LDB_G(buf, nh, dst) do { _Pragma("unroll") \
    for (int t = 0; t < 2; ++t) { _Pragma("unroll") \
      for (int ks = 0; ks < 2; ++ks) \
        dst[t * 2 + ks] = *(const bf16x8*)&smem[2 + (buf)][wn * 64 + (nh) * 32 + t * 16 + fr] \
                                              [(((ks << 2) | quad) ^ swz) << 3]; } } while (0)
// one C-quadrant x K=64: 16 MFMAs wrapped in setprio (T5)
#define MFMA_Q(mh, nh, bb) do { \
    __builtin_amdgcn_s_setprio(1); \
    _Pragma("unroll") \
    for (int t = 0; t < 4; ++t) { _Pragma("unroll") \
      for (int u = 0; u < 2; ++u) { _Pragma("unroll") \
        for (int ks = 0; ks < 2; ++ks) \
          acc[(mh) * 4 + t][(nh) * 2 + u] = __builtin_amdgcn_mfma_f32_16x16x32_bf16( \
              av[t * 2 + ks], bb[u * 2 + ks], acc[(mh) * 4 + t][(nh) * 2 + u], 0, 0, 0); } } \
    __builtin_amdgcn_s_setprio(0); } while (0)

  bf16x8 av[8], b0[4], b1[4];
  f32x4 acc[8][4] = {};

  // prologue: buf0 full, B(buf1), A-lo(buf1) = 14 loads; vmcnt(6) lands buf0.
  STAGE_A(0, 0, 0); STAGE_A(0, 1, 0);
  STAGE_B(0, 0, 0); STAGE_B(0, 1, 0);
  STAGE_B(1, 0, 1); STAGE_B(1, 1, 1);
  STAGE_A(1, 0, 1);
  WAITV6(); BAR();

  const int KT = K >> 6;        // K-tiles
  const int NI = KT >> 1;       // iterations (2 K-tiles each)
  for (int i = 0; i < NI; ++i) {
    const int kt1 = 2 * i + 1;
    const int ka  = (2 * i + 2 < KT) ? 2 * i + 2 : 0;   // clamped prefetch
    const int kb  = (2 * i + 3 < KT) ? 2 * i + 3 : 0;

    // p0: quadrant (0,0) on buf0; stage A-hi(buf1,kt1)
    LDA_G(0, 0); LDB_G(0, 0, b0); STAGE_A(1, 1, kt1);
    LHINT8();
    BAR(); WAITL0(); MFMA_Q(0, 0, b0); BAR();
    // p1: (0,1)
    LDB_G(0, 1, b1);
    BAR(); WAITL0(); MFMA_Q(0, 1, b1); BAR();
    // p2: (1,1)
    LDA_G(0, 1); STAGE_B(0, 0, ka);
    BAR(); WAITL0(); MFMA_Q(1, 1, b1); BAR();
    // p3: (1,0)  [b0 kept live from p0]; wait covers buf1 (all >=3 phases old)
    STAGE_B(0, 1, ka); WAITV4();
    BAR(); WAITL0(); MFMA_Q(1, 0, b0); BAR();
    // p4: (0,0) on buf1
    LDA_G(1, 0); LDB_G(1, 0, b0); STAGE_A(0, 0, ka);
    LHINT8();
    BAR(); WAITL0(); MFMA_Q(0, 0, b0); BAR();
    // p5: (0,1)
    LDB_G(1, 1, b1); STAGE_A(0, 1, ka);
    BAR(); WAITL0(); MFMA_Q(0, 1, b1); BAR();
    // p6: (1,1)
    LDA_G(1, 1); STAGE_B(1, 0, kb);
    BAR(); WAITL0(); MFMA_Q(1, 1, b1); BAR();
    // p7: (1,0); stage B-hi(buf1,kb) + A-lo(buf1,kb); wait covers buf0'
    STAGE_B(1, 1, kb); STAGE_A(1, 0, kb); WAITV6();
    BAR(); WAITL0(); MFMA_Q(1, 0, b0); BAR();
  }
  // drain tail GLLs (all waves) before LDS is reused by the repack epilogue
  WAITV0(); BAR();

  // ------------------------------------------------------------------
  // Epilogue: LDS-repack for coalesced wide stores (fixes 2x HBM write
  // amplification of scattered 32B-segment stores).  Each wave uses its
  // private 16 KiB chunk; XOR-chunk swizzle keeps ds traffic ~conflict-free.
  // C/D frag layout (m89/m91): col = lane&15, row = quad*4 + r.
  // ------------------------------------------------------------------
  const int rq = quad * 4;
  char* myc = (char*)(&smem[0][0][0]) + wave * 16384;
  float bvv[4];
#pragma unroll
  for (int nj = 0; nj < 4; ++nj)
    bvv[nj] = bias ? bias[n0 + wn * 64 + nj * 16 + fr] : 0.0f;

  const int cn0 = n0 + wn * 64;

  if constexpr (sizeof(TC) == 2) {
    // bf16: whole 128x64 tile = 16 KiB in one pass
#pragma unroll
    for (int mi = 0; mi < 8; ++mi)
#pragma unroll
      for (int nj = 0; nj < 4; ++nj)
#pragma unroll
        for (int r = 0; r < 4; ++r) {
          const int row   = mi * 16 + rq + r;                  // 0..127
          const int chunk = ((nj << 1) | (fr >> 3)) ^ (row & 7);
          *(short*)(myc + row * 128 + chunk * 16 + (fr & 7) * 2) =
              bfbits(acc[mi][nj][r] + bvv[nj]);
        }
    asm volatile("s_waitcnt lgkmcnt(0)" ::: "memory");
    __builtin_amdgcn_sched_barrier(0);
    const int rr = lane >> 3, rc = (lane & 7) ^ (lane >> 3);
    size_t cbase;
    if constexpr (SPLIT3)
      cbase = ((size_t)(cn0 >> 10) << 24) + (size_t)(m0 + wm * 128) * 1024 + (cn0 & 1023);
    else
      cbase = (size_t)(m0 + wm * 128) * ldc + cn0;
    const int cstride = SPLIT3 ? 1024 : ldc;
#pragma unroll
    for (int j = 0; j < 16; ++j) {
      const int row = j * 8 + rr;                              // 0..127
      const uint4 d = *(const uint4*)(myc + row * 128 + rc * 16);
      *(uint4*)((bf16*)C + cbase + (size_t)row * cstride + (lane & 7) * 8) = d;
    }
  } else {
    // fp32: two 64-row passes of 16 KiB each
#pragma unroll
    for (int p = 0; p < 2; ++p) {
#pragma unroll
      for (int mi = 0; mi < 4; ++mi)
#pragma unroll
        for (int nj = 0; nj < 4; ++nj)
#pragma unroll
          for (int r = 0; r < 4; ++r) {
            const int row   = mi * 16 + rq + r;                // 0..63
            const int col   = nj * 16 + fr;
            const int chunk = (col >> 2) ^ (row & 7);
            *(float*)(myc + row * 256 + chunk * 16 + (col & 3) * 4) =
                acc[p * 4 + mi][nj][r] + bvv[nj];
          }
      asm volatile("s_waitcnt lgkmcnt(0)" ::: "memory");
      __builtin_amdgcn_sched_barrier(0);
      const int rr = lane >> 4, rc0 = lane & 15;
#pragma unroll
      for (int j = 0; j < 16; ++j) {
        const int row   = j * 4 + rr;                          // 0..63
        const int chunk = rc0 ^ (row & 7);
        const uint4 d = *(const uint4*)(myc + row * 256 + chunk * 16);
        *(uint4*)((float*)C + (size_t)(m0 + wm * 128 + p * 64 + row) * ldc
                  + cn0 + rc0 * 4) = d;
      }
      if (p == 0) {
        asm volatile("s_waitcnt lgkmcnt(0)" ::: "memory");     // reads done
        __builtin_amdgcn_sched_barrier(0);                     // before pass-1 writes
      }
    }
  }
#undef STAGE_A
#undef STAGE_B
#undef LDA_G
#undef LDB_G
#undef MFMA_Q
}

// Per-token head-attention on plane-packed q/k/v (each 16384 x 1024 bf16).
// One wave per token.  attn result overwrites the q plane.
__global__ __launch_bounds__(256)
void attn_heads(bf16* __restrict__ qp, const bf16* __restrict__ kp,
                const bf16* __restrict__ vp) {
  __shared__ __align__(16) bf16  s_qkv[4][3072];
  __shared__ __align__(16) float s_w[4][256];
  const int lane = threadIdx.x & 63;
  const int wave = threadIdx.x >> 6;
  const size_t tok = (size_t)blockIdx.x * 4 + wave;
  bf16*       qrow = qp + tok * 1024;
  const bf16* krow = kp + tok * 1024;
  const bf16* vrow = vp + tok * 1024;

#pragma unroll
  for (int i = 0; i < 2; ++i) {
    const int off = (i * 64 + lane) * 8;
    *(uint4*)(&s_qkv[wave][off])        = *(const uint4*)(qrow + off);
    *(uint4*)(&s_qkv[wave][1024 + off]) = *(const uint4*)(krow + off);
    *(uint4*)(&s_qkv[wave][2048 + off]) = *(const uint4*)(vrow + off);
  }
  __syncthreads();

  const bf16* sq = s_qkv[wave];
  const int fr   = lane & 15;
  const int quad = lane >> 4;

  // scores = q @ k^T via 2 MFMAs (K=64 -> 2 chunks of 32)
  f32x4 sc = {0.f, 0.f, 0.f, 0.f};
#pragma unroll
  for (int c = 0; c < 2; ++c) {
    bf16x8 a = *(const bf16x8*)&sq[fr * 64 + c * 32 + quad * 8];          // q[h=fr][k]
    bf16x8 b = *(const bf16x8*)&sq[1024 + fr * 64 + c * 32 + quad * 8];   // k[g=fr][k]
    sc = __builtin_amdgcn_mfma_f32_16x16x32_bf16(a, b, sc, 0, 0, 0);
  }

  // softmax over g (row h = quad*4+r lives across the 16 lanes of a quad)
#pragma unroll
  for (int r = 0; r < 4; ++r) {
    float s = sc[r] * 0.03125f;       // 1/sqrt(1024)
    float mx = s;
#pragma unroll
    for (int msk = 1; msk < 16; msk <<= 1) mx = fmaxf(mx, __shfl_xor(mx, msk, 64));
    float e = __expf(s - mx);
    float sum = e;
#pragma unroll
    for (int msk = 1; msk < 16; msk <<= 1) sum += __shfl_xor(sum, msk, 64);
    s_w[wave][(quad * 4 + r) * 16 + fr] = e / sum;
  }
  __syncthreads();

  // attn[h][d=lane] = sum_g w[h][g] * v[g][lane]; write into q plane
  float vv[16];
#pragma unroll
  for (int g = 0; g < 16; ++g) vv[g] = __bfloat162float(sq[2048 + g * 64 + lane]);
  const float* wrow = s_w[wave];
#pragma unroll
  for (int h = 0; h < 16; ++h) {
    float o = 0.f;
#pragma unroll
    for (int g4 = 0; g4 < 4; ++g4) {
      f32x4 w4 = *(const f32x4*)&wrow[h * 16 + g4 * 4];
      o += w4.x * vv[g4 * 4 + 0] + w4.y * vv[g4 * 4 + 1] +
           w4.z * vv[g4 * 4 + 2] + w4.w * vv[g4 * 4 + 3];
    }
    qrow[h * 64 + lane] = __float2bfloat16(o);
  }
}

extern "C" void kernel_launch(void* const* d_in, const int* in_sizes, int n_in,
                              void* d_out, int out_size, void* d_ws, size_t ws_size,
                              hipStream_t stream) {
  const float* x    = (const float*)d_in[0];   // (4,4096,1024) fp32
  const float* Wqkv = (const float*)d_in[1];   // (3072,1024) fp32
  const float* Wo   = (const float*)d_in[2];   // (1024,1024) fp32
  const float* bo   = (const float*)d_in[3];   // (1024,) fp32

  // Workspace (96 MiB): three 32 MiB planes q | k | v, each 16384x1024 bf16.
  bf16* qp = (bf16*)d_ws;
  bf16* kp = qp + ((size_t)1 << 24);
  bf16* vp = qp + ((size_t)2 << 24);

  // d_out doubles as pre-GEMM2 scratch: x_bf16 (32 MiB) + Wqkv_bf16 (6 MiB);
  // both dead before GEMM2 overwrites d_out (in-stream serialization).
  bf16* xb    = (bf16*)d_out;                  // 16,777,216 elems
  bf16* wqkvb = xb + 16777216;                 //  3,145,728 elems

  // 0) one-time fp32 -> bf16 conversions
  f32_to_bf16<<<8192, 256, 0, stream>>>(x, xb, 2097152);
  f32_to_bf16<<<1536, 256, 0, stream>>>(Wqkv, wqkvb, 393216);

  // 1) qkv = xb @ wqkvb^T (M=16384, N=3072, K=1024), plane-routed C write
  gemm256<bf16, true><<<768, 512, 0, stream>>>(
      xb, wqkvb, nullptr, qp, 1024, 1024, 1024, 1024, 12);

  // 2) per-token head attention; attn overwrites the q plane
  attn_heads<<<4096, 256, 0, stream>>>(qp, kp, vp);

  // 3) v plane is dead after attention -> convert Wo into it (2 MiB)
  f32_to_bf16<<<512, 256, 0, stream>>>(Wo, vp, 131072);

  // 4) out = attn @ Wo^T + bo  (M=16384, N=1024, K=1024), all lda/ldb/ldc=1024
  gemm256<float, false><<<256, 512, 0, stream>>>(
      qp, vp, bo, (float*)d_out, 1024, 1024, 1024, 1024, 4);
}